// Round 1
// baseline (281.879 us; speedup 1.0000x reference)
//
#include <hip/hip_runtime.h>
#include <stdint.h>

#define B 8
#define L 4096
#define C 1024
#define H 512
#define NPART 2048           // kA blocks: 256 per batch, 16 rows each
#define NPB 256              // kA partial blocks per batch
#define CCH 16               // c-chunk for k4bc (128 blocks)
#define CC4A 32              // c-chunk for k4a (256 blocks)

typedef float nfloat4 __attribute__((ext_vector_type(4)));

// ---- K_A: fused t1 + exp + weighted accumulate, single pass over x ----
// 2048 blocks; block handles 16 rows of one batch; wave handles 4 rows,
// fully unrolled so 16 float4 loads (1 KB/wave) are in flight before the
// dependent dot/shuffle/exp chain. Lane holds 16 cols (float4 at lane+64k).
// Block LDS-combines -> one 4 KB partial per block. Blocks<48 also zero
// the MLP atomic targets (pooled/u4raw/u5raw, 12288 floats).
__global__ __launch_bounds__(256) void kA_fused(const float* __restrict__ x,
                                                const float* __restrict__ w1,
                                                const float* __restrict__ b1,
                                                float* __restrict__ partial_xa,
                                                float* __restrict__ partial_s,
                                                float* __restrict__ zero_targets) {
    __shared__ float4 lds[4][256];
    __shared__ float ldsS[4];
    int t = threadIdx.x;
    int wave = t >> 6, lane = t & 63;
    int b = blockIdx.x >> 8;          // 256 blocks per batch
    int blkInB = blockIdx.x & 255;
    int l0 = blkInB * 16 + wave * 4;
    float b1v = b1[0];

    if (blockIdx.x < 48) zero_targets[blockIdx.x * 256 + t] = 0.f;  // 12288 floats

    const float4* w1v = (const float4*)w1;
    float4 wf[4];
#pragma unroll
    for (int k = 0; k < 4; ++k) wf[k] = w1v[lane + 64 * k];

    // issue all 16 row-loads up front (4 rows x 4 float4) for MLP depth
    const float4* row0 = (const float4*)(x + ((size_t)(b * L + l0)) * C);
    float4 xv[4][4];
#pragma unroll
    for (int r = 0; r < 4; ++r)
#pragma unroll
        for (int k = 0; k < 4; ++k)
            xv[r][k] = row0[r * 256 + lane + 64 * k];

    float4 acc[4];
#pragma unroll
    for (int k = 0; k < 4; ++k) acc[k] = make_float4(0.f, 0.f, 0.f, 0.f);
    float sexp = 0.f;

#pragma unroll
    for (int r = 0; r < 4; ++r) {
        float d = 0.f;
#pragma unroll
        for (int k = 0; k < 4; ++k)
            d += xv[r][k].x * wf[k].x + xv[r][k].y * wf[k].y
               + xv[r][k].z * wf[k].z + xv[r][k].w * wf[k].w;
#pragma unroll
        for (int off = 32; off > 0; off >>= 1) d += __shfl_xor(d, off, 64);
        float e = __expf(d + b1v);   // |t1| ~ O(3): safe without max subtraction
        sexp += e;
#pragma unroll
        for (int k = 0; k < 4; ++k) {
            acc[k].x += e * xv[r][k].x;
            acc[k].y += e * xv[r][k].y;
            acc[k].z += e * xv[r][k].z;
            acc[k].w += e * xv[r][k].w;
        }
    }
#pragma unroll
    for (int k = 0; k < 4; ++k) lds[wave][lane + 64 * k] = acc[k];
    if (lane == 0) ldsS[wave] = sexp;
    __syncthreads();
    float4 s0 = lds[0][t], s1 = lds[1][t], s2 = lds[2][t], s3 = lds[3][t];
    float4 s4;
    s4.x = (s0.x + s1.x) + (s2.x + s3.x);
    s4.y = (s0.y + s1.y) + (s2.y + s3.y);
    s4.z = (s0.z + s1.z) + (s2.z + s3.z);
    s4.w = (s0.w + s1.w) + (s2.w + s3.w);
    ((float4*)partial_xa)[(size_t)blockIdx.x * 256 + t] = s4;
    if (t == 0) partial_s[blockIdx.x] = (ldsS[0] + ldsS[1]) + (ldsS[2] + ldsS[3]);
}

// ---- k4a: reduce 256 partials -> normalized xa slice; GEMV w2 -> pooled
// grid 256: b = blk>>5, cc = blk&31 (32-col chunk). Reduction reads are
// 128 B coalesced per row (lanes 0-31 read consecutive cols of one row).
__global__ __launch_bounds__(256) void k4a_pooled(const float* __restrict__ partial_xa,
                                                  const float* __restrict__ partial_s,
                                                  const float* __restrict__ w2,
                                                  const float* __restrict__ b2,
                                                  float* __restrict__ pooled) {
    __shared__ float red[8][CC4A];
    __shared__ float xs[CC4A];
    __shared__ float sred[4];
    __shared__ float invS;
    int t = threadIdx.x;
    int b = blockIdx.x >> 5;
    int cc = blockIdx.x & 31;
    int c0 = cc * CC4A;
    int wave = t >> 6, lane = t & 63;

    // softmax denominator: sum 256 partial_s of this batch
    float ps = partial_s[b * NPB + t];
#pragma unroll
    for (int off = 32; off > 0; off >>= 1) ps += __shfl_xor(ps, off, 64);
    if (lane == 0) sred[wave] = ps;

    // xs reduce: thread (jg = t>>5, ci = t&31) sums 32 of 256 partial rows
    {
        int ci = t & 31, jg = t >> 5;
        float a = 0.f;
        const float* src = partial_xa + ((size_t)(b * NPB + jg * 32)) * C + c0 + ci;
#pragma unroll 8
        for (int i = 0; i < 32; ++i) a += src[(size_t)i * C];
        __syncthreads();                 // sred visible
        if (t == 0) invS = 1.f / ((sred[0] + sred[1]) + (sred[2] + sred[3]));
        red[jg][ci] = a;
    }
    __syncthreads();
    if (t < CC4A) {
        float a = 0.f;
#pragma unroll
        for (int q = 0; q < 8; ++q) a += red[q][t];
        xs[t] = a * invS;
    }
    __syncthreads();

    // GEMV: thread handles h = t and h = t + 256 (coalesced w2 reads)
    float a0 = 0.f, a1 = 0.f;
#pragma unroll 8
    for (int ci = 0; ci < CC4A; ++ci) {
        float xc = xs[ci];
        a0 += xc * w2[(size_t)(c0 + ci) * H + t];
        a1 += xc * w2[(size_t)(c0 + ci) * H + 256 + t];
    }
    if (cc == 0) { a0 += b2[t]; a1 += b2[t + 256]; }
    atomicAdd(&pooled[b * H + t], a0);
    atomicAdd(&pooled[b * H + 256 + t], a1);
}

// ---- k4bc: fused v-compute (from pooled) + u4/u5 accumulation ---------
// grid 128: hg = blk&1 (h half), cc = blk>>1 (c chunk of 16)
__global__ __launch_bounds__(256) void k4bc(const float* __restrict__ pooled,
                                            const float* __restrict__ w3,
                                            const float* __restrict__ b3,
                                            const float* __restrict__ w4,
                                            const float* __restrict__ w5,
                                            float* __restrict__ u4raw,
                                            float* __restrict__ u5raw) {
    __shared__ float pooledS[B][H];         // 16 KB
    __shared__ float vpart[16][B][CCH];     // 8 KB: 16 h-quarters of 32 h
    __shared__ float vs[B][CCH];            // 512 B
    int hg = blockIdx.x & 1;
    int cc = blockIdx.x >> 1;               // 0..63
    int c0 = cc * CCH;
    int t = threadIdx.x;

    for (int i = t; i < B * H; i += 256) ((float*)pooledS)[i] = pooled[i];
    __syncthreads();

    {   // stage 1: vraw slice; thread group hq covers 32 h values
        int ci = t & 15;
        int hq = t >> 4;                    // 0..15
        float a[B] = {0.f, 0.f, 0.f, 0.f, 0.f, 0.f, 0.f, 0.f};
        for (int hh = 0; hh < 32; ++hh) {
            int h = hq * 32 + hh;
            float w = w3[(size_t)h * C + c0 + ci];
#pragma unroll
            for (int bb = 0; bb < B; ++bb) a[bb] += pooledS[bb][h] * w;
        }
#pragma unroll
        for (int bb = 0; bb < B; ++bb) vpart[hq][bb][ci] = a[bb];
    }
    __syncthreads();
    if (t < B * CCH) {  // combine quarters + bias + sigmoid (128 values)
        int bb = t >> 4, ci = t & 15;
        float v = b3[c0 + ci];
#pragma unroll
        for (int q = 0; q < 16; ++q) v += vpart[q][bb][ci];
        vs[bb][ci] = 1.f / (1.f + __expf(-v));
    }
    __syncthreads();
    {   // stage 2: u4/u5 accumulation
        int h = hg * 256 + t;
        float a4[B] = {0.f, 0.f, 0.f, 0.f, 0.f, 0.f, 0.f, 0.f};
        float a5[B] = {0.f, 0.f, 0.f, 0.f, 0.f, 0.f, 0.f, 0.f};
#pragma unroll
        for (int ci = 0; ci < CCH; ++ci) {
            float wa = w4[(size_t)(c0 + ci) * H + h];
            float wb = w5[(size_t)(c0 + ci) * H + h];
#pragma unroll
            for (int bb = 0; bb < B; ++bb) {
                a4[bb] += vs[bb][ci] * wa;
                a5[bb] += vs[bb][ci] * wb;
            }
        }
#pragma unroll
        for (int bb = 0; bb < B; ++bb) {
            atomicAdd(&u4raw[bb * H + h], a4[bb]);
            atomicAdd(&u5raw[bb * H + h], a5[bb]);
        }
    }
}

// ---- k5: per-block redundant scal[b] dot + fill its 64 KB region ------
// grid 2048: b = blk>>8, region = blk&255 (16384 floats each).
// Wave shuffle reduce (1 barrier), nontemporal streaming stores.
__global__ __launch_bounds__(256) void k5_fill(const float* __restrict__ u4raw, const float* __restrict__ b4,
                                               const float* __restrict__ u5raw, const float* __restrict__ b5,
                                               float* __restrict__ out) {
    __shared__ float r4[4];
    int blk = blockIdx.x, t = threadIdx.x;
    int b = blk >> 8;
    int rg = blk & 255;
    float s = (u4raw[b * H + t] + b4[t]) * (u5raw[b * H + t] + b5[t])
            + (u4raw[b * H + 256 + t] + b4[256 + t]) * (u5raw[b * H + 256 + t] + b5[256 + t]);
#pragma unroll
    for (int off = 32; off > 0; off >>= 1) s += __shfl_xor(s, off, 64);
    if ((t & 63) == 0) r4[t >> 6] = s;
    __syncthreads();
    float tot = (r4[0] + r4[1]) + (r4[2] + r4[3]);
    float sc = 1.f / (1.f + __expf(-tot));
    nfloat4 s4 = {sc, sc, sc, sc};
    nfloat4* o = (nfloat4*)out + (size_t)b * (L * C / 4) + (size_t)rg * 4096;
#pragma unroll
    for (int k = 0; k < 16; ++k)
        __builtin_nontemporal_store(s4, &o[t + 256 * k]);
}

extern "C" void kernel_launch(void* const* d_in, const int* in_sizes, int n_in,
                              void* d_out, int out_size, void* d_ws, size_t ws_size,
                              hipStream_t stream) {
    const float* x  = (const float*)d_in[0];
    const float* w1 = (const float*)d_in[1];
    const float* b1 = (const float*)d_in[2];
    const float* w2 = (const float*)d_in[3];
    const float* b2 = (const float*)d_in[4];
    const float* w3 = (const float*)d_in[5];
    const float* b3 = (const float*)d_in[6];
    const float* w4 = (const float*)d_in[7];
    const float* b4 = (const float*)d_in[8];
    const float* w5 = (const float*)d_in[9];
    const float* b5 = (const float*)d_in[10];

    float* ws         = (float*)d_ws;
    float* partial_xa = ws;                          // NPART*C = 2M floats (8 MB)
    float* partial_s  = partial_xa + (size_t)NPART * C;  // 2048
    float* pooled     = partial_s + NPART;           // B*H = 4096   } contiguous
    float* u4raw      = pooled + B * H;              // B*H = 4096   } zero block
    float* u5raw      = u4raw + B * H;               // B*H = 4096   } (12288 floats)

    kA_fused<<<NPART, 256, 0, stream>>>(x, w1, b1, partial_xa, partial_s, pooled);
    k4a_pooled<<<256, 256, 0, stream>>>(partial_xa, partial_s, w2, b2, pooled);
    k4bc<<<128, 256, 0, stream>>>(pooled, w3, b3, w4, w5, u4raw, u5raw);
    k5_fill<<<2048, 256, 0, stream>>>(u4raw, b4, u5raw, b5, (float*)d_out);
}